// Round 3
// baseline (262.909 us; speedup 1.0000x reference)
//
#include <hip/hip_runtime.h>
#include <hip/hip_bf16.h>

#define BB   2
#define NN   128
#define SS   4
#define DGG  8
#define CIN  4
#define COUT 8
#define HH   32

typedef __attribute__((ext_vector_type(4))) float          fvec4;
typedef __attribute__((ext_vector_type(4))) unsigned short usvec4;
typedef __attribute__((ext_vector_type(8))) unsigned short usvec8;

// LDS layout (float offsets)
#define O_YW1  0      // ky_W1: 4*32*2   = 256
#define O_YB1  256    // ky_b1: 4*32     = 128
#define O_YW2  384    // ky_W2: 4*32*32  = 4096
#define O_YB2  4480   // ky_b2: 128
#define O_YW3  4608   // ky_W3: 128
#define O_YB3  4736   // ky_b3: 4
#define O_GW1  4740   // kg_W1: 4*32*8   = 1024
#define O_GB1  5764   // kg_b1: 128
#define O_GW2  5892   // kg_W2: 4096
#define O_GB2  9988   // kg_b2: 128
#define O_GW3  10116  // kg_W3: 128
#define O_GB3  10244  // kg_b3: 4
#define W_TOTAL 10248
#define O_PART  W_TOTAL          // 8 waves * 4 s1 * 8 = 256
#define SM_TOTAL (W_TOTAL + 256)

__device__ __forceinline__ float bf2f(unsigned short u) {
    return __uint_as_float(((unsigned int)u) << 16);
}

// minimal silu: v_mul, v_exp, v_add, v_rcp, v_mul (exp/rcp quarter-rate)
__device__ __forceinline__ float silu_f(float x) {
    float e = __builtin_amdgcn_exp2f(x * -1.44269504f);
    return x * __builtin_amdgcn_rcpf(1.0f + e);
}
__device__ __forceinline__ float exp_f(float x) {
    return __builtin_amdgcn_exp2f(x * 1.44269504f);
}

// ---- dtype detection (deterministic, graph-capture safe) ----
// modes[0]: 0 = float tensors are f32, 1 = bf16
// modes[1]: mask dtype: 0=i32, 1=bf16, 2=u8/bool, 3=f32
__global__ void detect_kernel(const void* maskp, const void* cosetp, int* modes) {
    int lane = threadIdx.x;  // 64 threads
    const unsigned short* cu = (const unsigned short*)cosetp;
    unsigned short v = cu[2 * lane];
    int e = (v >> 7) & 0xFF;
    int hit = (e >= 110 && e <= 135) ? 1 : 0;
    int hits = __popcll(__ballot(hit));
    int fmode = (hits > 32) ? 1 : 0;

    const unsigned short* mu = (const unsigned short*)maskp;
    int evenBF = 0, any3 = 0, anyByte = 0;
    for (int r = 0; r < 8; ++r) {
        int idx = lane + r * 64;
        unsigned short m = mu[idx];
        if (m == 0x3F80) { any3 = 1; if (!(idx & 1)) evenBF = 1; }
        if (m == 0x0101 || m == 0x0100) anyByte = 1;
    }
    evenBF  = (__ballot(evenBF)  != 0ull);
    any3    = (__ballot(any3)    != 0ull);
    anyByte = (__ballot(anyByte) != 0ull);
    if (lane == 0) {
        modes[0] = fmode;
        modes[1] = evenBF ? 1 : (any3 ? 3 : (anyByte ? 2 : 0));
    }
}

__device__ __forceinline__ void copy_arr(float* sm, const void* src, int off,
                                         int cnt, int fmode, int tid) {
    if (fmode) {
        const unsigned short* s = (const unsigned short*)src;
        for (int x = tid; x < cnt; x += 512) sm[off + x] = bf2f(s[x]);
    } else {
        const float* s = (const float*)src;
        for (int x = tid; x < cnt; x += 512) sm[off + x] = s[x];
    }
}

__device__ __forceinline__ void load4(const void* p, int base, int fmode, float* dst) {
    if (fmode) {
        usvec4 v = *(const usvec4*)((const unsigned short*)p + base);
        dst[0] = bf2f(v[0]); dst[1] = bf2f(v[1]);
        dst[2] = bf2f(v[2]); dst[3] = bf2f(v[3]);
    } else {
        fvec4 v = *(const fvec4*)((const float*)p + base);
        dst[0] = v[0]; dst[1] = v[1]; dst[2] = v[2]; dst[3] = v[3];
    }
}

__device__ __forceinline__ void load8(const void* p, int base, int fmode, float* dst) {
    if (fmode) {
        usvec8 v = *(const usvec8*)((const unsigned short*)p + base);
#pragma unroll
        for (int d = 0; d < 8; ++d) dst[d] = bf2f(v[d]);
    } else {
        fvec4 a = *(const fvec4*)((const float*)p + base);
        fvec4 b = *(const fvec4*)((const float*)p + base + 4);
        dst[0] = a[0]; dst[1] = a[1]; dst[2] = a[2]; dst[3] = a[3];
        dst[4] = b[0]; dst[5] = b[1]; dst[6] = b[2]; dst[7] = b[3];
    }
}

__device__ __forceinline__ int load_mask(const void* p, int idx, int mmode) {
    if (mmode == 0) return ((const int*)p)[idx] != 0;
    if (mmode == 1) return ((const unsigned short*)p)[idx] != 0;
    if (mmode == 2) return ((const unsigned char*)p)[idx] != 0;
    return ((const unsigned int*)p)[idx] != 0;
}

// 512 blocks: blk = half*256 + b*128 + n1. 512 threads: t = n2b*16 + s1*4 + s2.
// Each thread covers n2 = half*64 + p*32 + n2b, p in {0,1} (P=2).
// 512 blocks -> 2 blocks/CU -> 4 waves/SIMD (round-2 had 2 waves/SIMD and
// VALUBusy stuck at 71%).  Partial (num,den) sums per (s1,i) go to d_ws slot
// [half][bn][s1][8]; finalize_kernel combines halves (deterministic, no
// atomics, no memset needed since every slot is written).
__global__ __launch_bounds__(512, 4) void emha_partial(
    const void* __restrict__ g_pw, const void* __restrict__ g_coset,
    const void* __restrict__ g_mask,
    const void* yW1, const void* yb1, const void* yW2, const void* yb2,
    const void* yW3, const void* yb3,
    const void* gW1, const void* gb1, const void* gW2, const void* gb2,
    const void* gW3, const void* gb3,
    const int* modes, float* part)
{
    __shared__ float sm[SM_TOTAL];
    const int tid = threadIdx.x;
    const int fmode = modes[0];
    const int mmode = modes[1];
    const int half = blockIdx.x >> 8;
    const int bn   = blockIdx.x & 255;
    const int b  = bn >> 7;
    const int n1 = bn & 127;

    copy_arr(sm, yW1, O_YW1, 256,  fmode, tid);
    copy_arr(sm, yb1, O_YB1, 128,  fmode, tid);
    copy_arr(sm, yW2, O_YW2, 4096, fmode, tid);
    copy_arr(sm, yb2, O_YB2, 128,  fmode, tid);
    copy_arr(sm, yW3, O_YW3, 128,  fmode, tid);
    copy_arr(sm, yb3, O_YB3, 4,    fmode, tid);
    copy_arr(sm, gW1, O_GW1, 1024, fmode, tid);
    copy_arr(sm, gb1, O_GB1, 128,  fmode, tid);
    copy_arr(sm, gW2, O_GW2, 4096, fmode, tid);
    copy_arr(sm, gb2, O_GB2, 128,  fmode, tid);
    copy_arr(sm, gW3, O_GW3, 128,  fmode, tid);
    copy_arr(sm, gb3, O_GB3, 4,    fmode, tid);
    __syncthreads();

    const int s2  = tid & 3;
    const int s1  = (tid >> 2) & 3;
    const int n2b = tid >> 4;

    float fb[4];
    load4(g_coset, ((b * NN + n1) * SS + s1) * CIN, fmode, fb);

    float fa[2][4];
    float gv[2][8];
    int   mbits = 0;
#pragma unroll
    for (int p = 0; p < 2; ++p) {
        const int n2 = half * 64 + p * 32 + n2b;
        const int pos = (((b * NN + n1) * NN + n2) * SS + s1) * SS + s2;
        load8(g_pw, pos * DGG, fmode, gv[p]);
        load4(g_coset, ((b * NN + n2) * SS + s2) * CIN, fmode, fa[p]);
        mbits |= load_mask(g_mask, (b * NN + n2) * SS + s2, mmode) << p;
    }

    float accN[4] = {0.f, 0.f, 0.f, 0.f};
    float accD[4] = {0.f, 0.f, 0.f, 0.f};

#pragma unroll
    for (int i = 0; i < CIN; ++i) {
        float h1[2][HH];
        // ---- ky layer 1 ----
        {
            const float* W1 = &sm[O_YW1 + i * 64];
            const float* B1 = &sm[O_YB1 + i * HH];
#pragma unroll
            for (int j = 0; j < HH; ++j) {
                float w0 = W1[2 * j], w1 = W1[2 * j + 1];
                float c = w1 * fb[i] + B1[j];
#pragma unroll
                for (int p = 0; p < 2; ++p)
                    h1[p][j] = silu_f(w0 * fa[p][i] + c);
            }
        }
        // ---- ky layers 2+3 fused ----
        float kyv[2];
        {
            const float* W2 = &sm[O_YW2 + i * 1024];
            const float* B2 = &sm[O_YB2 + i * HH];
            const float* W3 = &sm[O_YW3 + i * HH];
            float a3[2] = {0.f, 0.f};
#pragma unroll 2
            for (int j = 0; j < HH; ++j) {
                float d[2] = {0.f, 0.f};
#pragma unroll
                for (int k = 0; k < HH; ++k) {
                    float w = W2[j * HH + k];
#pragma unroll
                    for (int p = 0; p < 2; ++p) d[p] += w * h1[p][k];
                }
                float bb = B2[j], w3 = W3[j];
#pragma unroll
                for (int p = 0; p < 2; ++p) a3[p] += w3 * silu_f(d[p] + bb);
            }
            float b3 = sm[O_YB3 + i];
#pragma unroll
            for (int p = 0; p < 2; ++p) kyv[p] = silu_f(a3[p] + b3);
        }
        // ---- kg layer 1 ----
        {
            const float* W1 = &sm[O_GW1 + i * 256];
            const float* B1 = &sm[O_GB1 + i * HH];
#pragma unroll
            for (int j = 0; j < HH; ++j) {
                float bb = B1[j];
                float d[2] = {bb, bb};
#pragma unroll
                for (int d8 = 0; d8 < DGG; ++d8) {
                    float w = W1[j * DGG + d8];
#pragma unroll
                    for (int p = 0; p < 2; ++p) d[p] += w * gv[p][d8];
                }
#pragma unroll
                for (int p = 0; p < 2; ++p) h1[p][j] = silu_f(d[p]);
            }
        }
        // ---- kg layers 2+3 fused ----
        float kgv[2];
        {
            const float* W2 = &sm[O_GW2 + i * 1024];
            const float* B2 = &sm[O_GB2 + i * HH];
            const float* W3 = &sm[O_GW3 + i * HH];
            float a3[2] = {0.f, 0.f};
#pragma unroll 2
            for (int j = 0; j < HH; ++j) {
                float d[2] = {0.f, 0.f};
#pragma unroll
                for (int k = 0; k < HH; ++k) {
                    float w = W2[j * HH + k];
#pragma unroll
                    for (int p = 0; p < 2; ++p) d[p] += w * h1[p][k];
                }
                float bb = B2[j], w3 = W3[j];
#pragma unroll
                for (int p = 0; p < 2; ++p) a3[p] += w3 * silu_f(d[p] + bb);
            }
            float b3 = sm[O_GB3 + i];
#pragma unroll
            for (int p = 0; p < 2; ++p) kgv[p] = silu_f(a3[p] + b3);
        }
        // ---- masked exp, accumulate ----
#pragma unroll
        for (int p = 0; p < 2; ++p) {
            float e = ((mbits >> p) & 1) ? exp_f(kyv[p] + kgv[p]) : 0.f;
            accD[i] += e;
            accN[i] += e * fa[p][i];
        }
    }

    // Reduce over s2 (lane bits 0,1) and n2b-low (lane bits 4,5)
#pragma unroll
    for (int i = 0; i < CIN; ++i) {
        accN[i] += __shfl_xor(accN[i], 1);
        accD[i] += __shfl_xor(accD[i], 1);
        accN[i] += __shfl_xor(accN[i], 2);
        accD[i] += __shfl_xor(accD[i], 2);
        accN[i] += __shfl_xor(accN[i], 16);
        accD[i] += __shfl_xor(accD[i], 16);
        accN[i] += __shfl_xor(accN[i], 32);
        accD[i] += __shfl_xor(accD[i], 32);
    }
    const int lane = tid & 63;
    const int wave = tid >> 6;
    if ((lane & 51) == 0) {  // lanes 0,4,8,12: holders per s1
        const int ps1 = (lane >> 2) & 3;
        float* p = &sm[O_PART + (wave * 4 + ps1) * 8];
#pragma unroll
        for (int i = 0; i < CIN; ++i) {
            p[i * 2]     = accN[i];
            p[i * 2 + 1] = accD[i];
        }
    }
    __syncthreads();
    if (tid < 32) {
        const int ps1 = tid >> 3, j = tid & 7;
        float v = 0.f;
#pragma unroll
        for (int w = 0; w < 8; ++w) v += sm[O_PART + (w * 4 + ps1) * 8 + j];
        part[((half * 256 + bn) * 4 + ps1) * 8 + j] = v;
    }
}

// 1024 threads: one per (b, n1, s1). Combines the two halves' partials,
// applies f + num/den, query mask, and the w_out projection.
__global__ void finalize_kernel(const void* __restrict__ g_coset,
                                const void* __restrict__ g_mask,
                                const void* wout, const float* part,
                                const int* modes, void* outp) {
    const int t = blockIdx.x * 256 + threadIdx.x;  // [0,1024)
    const int fmode = modes[0], mmode = modes[1];
    const int bn = t >> 2;     // b*128+n1
    const int s1 = t & 3;
    const int b  = bn >> 7;

    float fb[4];
    load4(g_coset, (bn * SS + s1) * CIN, fmode, fb);
    const int m1 = load_mask(g_mask, bn * SS + s1, mmode);
    (void)b;

    float cf[4];
#pragma unroll
    for (int i = 0; i < CIN; ++i) {
        const int b0 = (bn * 4 + s1) * 8 + i * 2;
        const int b1 = ((256 + bn) * 4 + s1) * 8 + i * 2;
        float num = part[b0] + part[b1];
        float den = part[b0 + 1] + part[b1 + 1];
        cf[i] = m1 ? (fb[i] + num * __builtin_amdgcn_rcpf(den)) : 0.f;
    }
#pragma unroll
    for (int o = 0; o < COUT; ++o) {
        float wv[4];
        load4(wout, o * CIN, fmode, wv);
        float v = cf[0] * wv[0] + cf[1] * wv[1] + cf[2] * wv[2] + cf[3] * wv[3];
        const int oidx = (bn * SS + s1) * COUT + o;
        if (fmode) ((__hip_bfloat16*)outp)[oidx] = __float2bfloat16(v);
        else       ((float*)outp)[oidx] = v;
    }
}

extern "C" void kernel_launch(void* const* d_in, const int* in_sizes, int n_in,
                              void* d_out, int out_size, void* d_ws, size_t ws_size,
                              hipStream_t stream) {
    int*   modes = (int*)d_ws;                       // 2 ints
    float* part  = (float*)((char*)d_ws + 256);      // 2*256*4*8 = 16384 floats
    detect_kernel<<<1, 64, 0, stream>>>(d_in[2], d_in[1], modes);
    emha_partial<<<2 * BB * NN, 512, 0, stream>>>(
        d_in[0], d_in[1], d_in[2],
        d_in[3], d_in[4], d_in[5], d_in[6], d_in[7], d_in[8],
        d_in[9], d_in[10], d_in[11], d_in[12], d_in[13], d_in[14],
        modes, part);
    finalize_kernel<<<4, 256, 0, stream>>>(d_in[1], d_in[2], d_in[15], part,
                                           modes, d_out);
}